// Round 4
// baseline (1438.815 us; speedup 1.0000x reference)
//
#include <hip/hip_runtime.h>
#include <stdint.h>

#define DGRID 128
#define D3 (DGRID * DGRID * DGRID)
#define NBATCH 2
#define NPTS 150000
#define NROWS (NBATCH * NPTS)
#define NPAD 300032            // ceil(NROWS/64)*64
#define ZROW NROWS             // dedicated all-zero row of h
#define NCBLK (NPAD / 128)     // 2344 conv blocks (4 waves x 32 rows)
#define EPSBN 1e-4f
#define SBLK 1024

typedef __attribute__((ext_vector_type(8))) short s16x8;
typedef __attribute__((ext_vector_type(4))) float f32x4;

static __device__ __forceinline__ uint32_t f2bf_rne(float f) {
  uint32_t b = __float_as_uint(f);
  return (b + 0x7FFFu + ((b >> 16) & 1u)) >> 16;
}

static __device__ __forceinline__ f32x4 mfma16(uint4 a, uint4 b, f32x4 c) {
  return __builtin_amdgcn_mfma_f32_16x16x32_bf16(
      __builtin_bit_cast(s16x8, a), __builtin_bit_cast(s16x8, b), c, 0, 0, 0);
}

// scatter point indices into dense voxel LUT (codes unique per sample)
__global__ void k_scatter(const int* __restrict__ pos, int* __restrict__ lut) {
  int g = blockIdx.x * blockDim.x + threadIdx.x;
  if (g >= NROWS) return;
  int b = g / NPTS;
  int i = g - b * NPTS;
  int x = pos[3 * g], y = pos[3 * g + 1], z = pos[3 * g + 2];
  lut[(size_t)b * D3 + (x * DGRID + y) * DGRID + z] = i;
}

// dense tap-major neighbor table; invalid/missing/pad -> ZROW (zero row)
__global__ void k_nbr(const int* __restrict__ pos, const int* __restrict__ lut,
                      int* __restrict__ nbr) {
  int g = blockIdx.x * blockDim.x + threadIdx.x;
  if (g >= NPAD) return;
  if (g >= NROWS) {
#pragma unroll
    for (int t = 0; t < 27; ++t) nbr[(size_t)t * NPAD + g] = ZROW;
    return;
  }
  int b = g / NPTS;
  int x = pos[3 * g], y = pos[3 * g + 1], z = pos[3 * g + 2];
  const int* L = lut + (size_t)b * D3;
#pragma unroll
  for (int t = 0; t < 27; ++t) {
    int nx = x + t / 9 - 1;
    int ny = y + (t / 3) % 3 - 1;
    int nz = z + t % 3 - 1;
    int v = ZROW;
    if ((unsigned)nx < DGRID && (unsigned)ny < DGRID && (unsigned)nz < DGRID) {
      int n = L[(nx * DGRID + ny) * DGRID + nz];
      if (n >= 0) v = b * NPTS + n;
    }
    nbr[(size_t)t * NPAD + g] = v;
  }
}

// pack W into exact mfma_16x16x32_bf16 B-fragment layout:
// Wfrag[((cid*27+t)*2+s)*256 + nb*64 + lane]
__global__ void k_wpack(const float* __restrict__ Ws, uint4* __restrict__ Wfrag) {
  int e = blockIdx.x * 256 + threadIdx.x;
  if (e >= 4 * 27 * 512) return;
  int lane = e & 63, nb = (e >> 6) & 3, s = (e >> 8) & 1, tt = e >> 9;
  int kb = s * 32 + (lane >> 4) * 8;
  int cout = nb * 16 + (lane & 15);
  const float* src = Ws + (size_t)tt * 4096;
  uint32_t p[4];
#pragma unroll
  for (int j = 0; j < 4; ++j) {
    uint32_t lo = f2bf_rne(src[(kb + 2 * j) * 64 + cout]);
    uint32_t hi = f2bf_rne(src[(kb + 2 * j + 1) * 64 + cout]);
    p[j] = (hi << 16) | lo;
  }
  uint4 o;
  o.x = p[0]; o.y = p[1]; o.z = p[2]; o.w = p[3];
  Wfrag[e] = o;
}

// stage-1 BN stats over a f32 [NROWS][64] tensor (feats only)
__global__ void k_stats1(const float* __restrict__ X, float* __restrict__ part) {
  __shared__ float s[512];
  int c = threadIdx.x & 63, q = threadIdx.x >> 6;
  float sm = 0.f, sq = 0.f;
  for (int r = blockIdx.x * 4 + q; r < NROWS; r += SBLK * 4) {
    float v = X[(size_t)r * 64 + c];
    sm += v;
    sq += v * v;
  }
  s[threadIdx.x] = sm;
  s[256 + threadIdx.x] = sq;
  __syncthreads();
  if (q == 0) {
    sm = s[c] + s[64 + c] + s[128 + c] + s[192 + c];
    sq = s[256 + c] + s[320 + c] + s[384 + c] + s[448 + c];
    part[blockIdx.x * 128 + c] = sm;
    part[blockIdx.x * 128 + 64 + c] = sq;
  }
}

// stage-2: reduce nblk partials -> affine (a, b') with bnrelu(x)=relu(x*a+b')
__global__ void k_stats2(const float* __restrict__ part, int nblk,
                         const float* __restrict__ gamma, const float* __restrict__ beta,
                         float* __restrict__ chanp, int cid) {
  __shared__ float s[512];
  int c = threadIdx.x & 63, q = threadIdx.x >> 6;
  float sm = 0.f, sq = 0.f;
  for (int rb = q; rb < nblk; rb += 4) {
    sm += part[rb * 128 + c];
    sq += part[rb * 128 + 64 + c];
  }
  s[threadIdx.x] = sm;
  s[256 + threadIdx.x] = sq;
  __syncthreads();
  if (q == 0) {
    sm = s[c] + s[64 + c] + s[128 + c] + s[192 + c];
    sq = s[256 + c] + s[320 + c] + s[384 + c] + s[448 + c];
    float mean = sm / (float)NROWS;
    float var = sq / (float)NROWS - mean * mean;
    float a = gamma[cid * 64 + c] * rsqrtf(var + EPSBN);
    chanp[cid * 128 + c] = a;
    chanp[cid * 128 + 64 + c] = beta[cid * 64 + c] - mean * a;
  }
}

// h = bnrelu(X) cast to bf16 rows of 64 -> [NPAD][8] uint4; row ZROW = zeros
__global__ void k_hpass(const float* __restrict__ X, const float* __restrict__ chanp,
                        int cid, uint4* __restrict__ h) {
  int g = blockIdx.x * blockDim.x + threadIdx.x;
  if (g >= (NROWS + 1) * 8) return;
  if (g >= NROWS * 8) {
    h[g] = (uint4){0u, 0u, 0u, 0u};
    return;
  }
  int c0 = (g & 7) * 8;
  const float* cp = chanp + cid * 128;
  const float4 a0 = *(const float4*)(cp + c0);
  const float4 a1 = *(const float4*)(cp + c0 + 4);
  const float4 b0 = *(const float4*)(cp + 64 + c0);
  const float4 b1 = *(const float4*)(cp + 64 + c0 + 4);
  const float4 x0 = *(const float4*)(X + (size_t)g * 8);
  const float4 x1 = *(const float4*)(X + (size_t)g * 8 + 4);
  float v0 = fmaxf(fmaf(x0.x, a0.x, b0.x), 0.f);
  float v1 = fmaxf(fmaf(x0.y, a0.y, b0.y), 0.f);
  float v2 = fmaxf(fmaf(x0.z, a0.z, b0.z), 0.f);
  float v3 = fmaxf(fmaf(x0.w, a0.w, b0.w), 0.f);
  float v4 = fmaxf(fmaf(x1.x, a1.x, b1.x), 0.f);
  float v5 = fmaxf(fmaf(x1.y, a1.y, b1.y), 0.f);
  float v6 = fmaxf(fmaf(x1.z, a1.z, b1.z), 0.f);
  float v7 = fmaxf(fmaf(x1.w, a1.w, b1.w), 0.f);
  uint4 o;
  o.x = (f2bf_rne(v1) << 16) | f2bf_rne(v0);
  o.y = (f2bf_rne(v3) << 16) | f2bf_rne(v2);
  o.z = (f2bf_rne(v5) << 16) | f2bf_rne(v4);
  o.w = (f2bf_rne(v7) << 16) | f2bf_rne(v6);
  h[g] = o;
}

// One pipeline phase (tap T). FIFO-aware issue order:
//   1. W(T+1) -> WN   (issued FIRST so waiting for it never drains A)
//   2. ni(T+2) -> NIL
//   3. A(T+1) gathers -> AN (using NIA = ni(T+1))
//   4. MFMA(T) on AC x WC  (compiler wait leaves step 1-3 loads in flight)
#define PH(T, WC, WN, AC, AN, NIA, NIL)                                     \
  {                                                                         \
    int tw = (T) + 1 <= 26 ? (T) + 1 : 26;                                  \
    const uint4* Wt = Wf + (size_t)tw * 512 + lane;                         \
    _Pragma("unroll") for (int i = 0; i < 8; i++) WN[i] = Wt[i * 64];       \
    int tn = (T) + 2 <= 26 ? (T) + 2 : 26;                                  \
    NIL[0] = nbp[(size_t)tn * NPAD];                                        \
    NIL[1] = nbp[(size_t)tn * NPAD + 16];                                   \
    {                                                                       \
      const uint4* hp0 = h + (size_t)NIA[0] * 8 + lkg;                      \
      const uint4* hp1 = h + (size_t)NIA[1] * 8 + lkg;                      \
      AN[0][0] = hp0[0]; AN[0][1] = hp0[4];                                 \
      AN[1][0] = hp1[0]; AN[1][1] = hp1[4];                                 \
    }                                                                       \
    _Pragma("unroll") for (int s = 0; s < 2; s++)                           \
      _Pragma("unroll") for (int rt = 0; rt < 2; rt++)                      \
        _Pragma("unroll") for (int nb = 0; nb < 4; nb++)                    \
          acc[rt][nb] = mfma16(AC[rt][s], WC[s * 4 + nb], acc[rt][nb]);     \
  }

// MFMA conv: wave = 32 rows x 64 cout; dense 27 taps; branchless zero-row
// gathers; W/ni/A register pipeline with FIFO-correct issue order.
__global__ __launch_bounds__(256, 3) void k_conv(
    const uint4* __restrict__ h, const uint4* __restrict__ Wf,
    const int* __restrict__ nbr, const float* __restrict__ res,
    float* __restrict__ out, float* __restrict__ part, int do_stats) {
  __shared__ float xp[4][16 * 68];
  __shared__ float sred[2][4][4][16];
  int tid = threadIdx.x, wv = tid >> 6, lane = tid & 63;
  int tbase = (blockIdx.x * 4 + wv) * 32;
  int lrow = lane & 15, lkg = lane >> 4;

  f32x4 acc[2][4];
#pragma unroll
  for (int i = 0; i < 2; i++)
#pragma unroll
    for (int j = 0; j < 4; j++) acc[i][j] = (f32x4){0.f, 0.f, 0.f, 0.f};

  const int* nbp = nbr + tbase + lrow;
  int n0[2], n1[2];
  uint4 w0[8], w1[8];
  uint4 a0[2][2], a1[2][2];

  // prologue: ni(0) (temps), ni(1)->n1, W(0)->w0, A(0)->a0
  int p0 = nbp[0], p1 = nbp[16];
  n1[0] = nbp[NPAD];
  n1[1] = nbp[NPAD + 16];
#pragma unroll
  for (int i = 0; i < 8; i++) w0[i] = Wf[i * 64 + lane];
  {
    const uint4* hp0 = h + (size_t)p0 * 8 + lkg;
    const uint4* hp1 = h + (size_t)p1 * 8 + lkg;
    a0[0][0] = hp0[0]; a0[0][1] = hp0[4];
    a0[1][0] = hp1[0]; a0[1][1] = hp1[4];
  }

  for (int t = 0; t < 26; t += 2) {
    PH(t, w0, w1, a0, a1, n1, n0)
    PH(t + 1, w1, w0, a1, a0, n0, n1)
  }
  PH(26, w0, w1, a0, a1, n1, n0)

  // ---- epilogue: per-rt LDS transpose -> coalesced res/out, fused stats
  float smc[16], sqc[16];
#pragma unroll
  for (int j = 0; j < 16; j++) smc[j] = sqc[j] = 0.f;
  float* slab = xp[wv];
#pragma unroll 1
  for (int rt = 0; rt < 2; rt++) {
#pragma unroll
    for (int nb = 0; nb < 4; nb++)
#pragma unroll
      for (int r = 0; r < 4; r++)
        slab[(lkg * 4 + r) * 68 + nb * 16 + lrow] = acc[rt][nb][r];
    __syncthreads();
    int gr = tbase + rt * 16 + lrow;
    if (gr < NROWS) {
#pragma unroll
      for (int j = 0; j < 4; j++) {
        float4 vv = *(float4*)&slab[lrow * 68 + lkg * 16 + j * 4];
        size_t off = (size_t)gr * 64 + lkg * 16 + j * 4;
        if (res) {
          float4 rr = *(const float4*)(res + off);
          vv.x += rr.x; vv.y += rr.y; vv.z += rr.z; vv.w += rr.w;
        }
        *(float4*)(out + off) = vv;
        smc[j * 4 + 0] += vv.x; sqc[j * 4 + 0] += vv.x * vv.x;
        smc[j * 4 + 1] += vv.y; sqc[j * 4 + 1] += vv.y * vv.y;
        smc[j * 4 + 2] += vv.z; sqc[j * 4 + 2] += vv.z * vv.z;
        smc[j * 4 + 3] += vv.w; sqc[j * 4 + 3] += vv.w * vv.w;
      }
    }
    __syncthreads();
  }
  if (do_stats) {
#pragma unroll
    for (int j = 0; j < 16; j++) {
      smc[j] += __shfl_xor(smc[j], 1); sqc[j] += __shfl_xor(sqc[j], 1);
      smc[j] += __shfl_xor(smc[j], 2); sqc[j] += __shfl_xor(sqc[j], 2);
      smc[j] += __shfl_xor(smc[j], 4); sqc[j] += __shfl_xor(sqc[j], 4);
      smc[j] += __shfl_xor(smc[j], 8); sqc[j] += __shfl_xor(sqc[j], 8);
    }
    if (lrow == 0) {
#pragma unroll
      for (int j = 0; j < 16; j++) {
        sred[0][wv][lkg][j] = smc[j];
        sred[1][wv][lkg][j] = sqc[j];
      }
    }
    __syncthreads();
    if (tid < 64) {
      float s0 = 0.f, s1 = 0.f;
      int q = tid >> 4, c = tid & 15;
#pragma unroll
      for (int w = 0; w < 4; w++) {
        s0 += sred[0][w][q][c];
        s1 += sred[1][w][q][c];
      }
      part[blockIdx.x * 128 + tid] = s0;
      part[blockIdx.x * 128 + 64 + tid] = s1;
    }
  }
}

extern "C" void kernel_launch(void* const* d_in, const int* in_sizes, int n_in,
                              void* d_out, int out_size, void* d_ws, size_t ws_size,
                              hipStream_t stream) {
  const float* feats = (const float*)d_in[0];
  const float* Ws = (const float*)d_in[1];
  const float* gammas = (const float*)d_in[2];
  const float* betas = (const float*)d_in[3];
  const int* pos = (const int*)d_in[4];
  float* out = (float*)d_out;

  char* w = (char*)d_ws;
  auto alloc = [&](size_t b) {
    char* p = w;
    w += (b + 255) & ~(size_t)255;
    return p;
  };
  int* nbr = (int*)alloc((size_t)27 * NPAD * 4);           // 32.4 MB
  uint4* Wfrag = (uint4*)alloc((size_t)4 * 27 * 512 * 16); // 0.9 MB
  float* part = (float*)alloc((size_t)NCBLK * 128 * 4);    // 1.2 MB
  float* chanp = (float*)alloc((size_t)4 * 128 * 4);       // 2 KB
  uint4* h = (uint4*)alloc((size_t)NPAD * 128);            // 38.4 MB
  float* xbuf = (float*)alloc((size_t)NROWS * 64 * 4);     // 76.8 MB
  char* reg0 = alloc((size_t)NROWS * 64 * 4);              // 76.8 MB
  float* cbuf = (float*)reg0;
  int* lut = (int*)reg0;  // lut (16.8 MB) dead before cbuf first written

  hipMemsetAsync(lut, 0xFF, (size_t)NBATCH * D3 * 4, stream);
  int gpts = (NROWS + 255) / 256;
  k_scatter<<<gpts, 256, 0, stream>>>(pos, lut);
  k_nbr<<<NPAD / 256, 256, 0, stream>>>(pos, lut, nbr);
  k_wpack<<<216, 256, 0, stream>>>(Ws, Wfrag);

  k_stats1<<<SBLK, 256, 0, stream>>>(feats, part);
  k_stats2<<<1, 256, 0, stream>>>(part, SBLK, gammas, betas, chanp, 0);
  k_hpass<<<9376, 256, 0, stream>>>(feats, chanp, 0, h);
  k_conv<<<NCBLK, 256, 0, stream>>>(h, Wfrag + 0 * 27 * 512, nbr, nullptr, cbuf, part, 1);

  k_stats2<<<1, 256, 0, stream>>>(part, NCBLK, gammas, betas, chanp, 1);
  k_hpass<<<9376, 256, 0, stream>>>(cbuf, chanp, 1, h);
  k_conv<<<NCBLK, 256, 0, stream>>>(h, Wfrag + 1 * 27 * 512, nbr, feats, xbuf, part, 1);

  k_stats2<<<1, 256, 0, stream>>>(part, NCBLK, gammas, betas, chanp, 2);
  k_hpass<<<9376, 256, 0, stream>>>(xbuf, chanp, 2, h);
  k_conv<<<NCBLK, 256, 0, stream>>>(h, Wfrag + 2 * 27 * 512, nbr, nullptr, cbuf, part, 1);

  k_stats2<<<1, 256, 0, stream>>>(part, NCBLK, gammas, betas, chanp, 3);
  k_hpass<<<9376, 256, 0, stream>>>(cbuf, chanp, 3, h);
  k_conv<<<NCBLK, 256, 0, stream>>>(h, Wfrag + 3 * 27 * 512, nbr, xbuf, out, part, 0);
}

// Round 5
// 1363.259 us; speedup vs baseline: 1.0554x; 1.0554x over previous
//
#include <hip/hip_runtime.h>
#include <stdint.h>

#define DGRID 128
#define D3 (DGRID * DGRID * DGRID)
#define NBATCH 2
#define NPTS 150000
#define NROWS (NBATCH * NPTS)
#define NPAD 300032            // ceil(NROWS/64)*64
#define ZROW NROWS             // dedicated all-zero row of h (sorted space)
#define NCBLK (NPAD / 128)     // 2344 conv blocks (4 waves x 32 rows)
#define NCELLS 8192            // 2 batches x 16^3 macro-cells (8^3 voxels each)
#define EPSBN 1e-4f
#define SBLK 1024

typedef __attribute__((ext_vector_type(8))) short s16x8;
typedef __attribute__((ext_vector_type(4))) float f32x4;

static __device__ __forceinline__ uint32_t f2bf_rne(float f) {
  uint32_t b = __float_as_uint(f);
  return (b + 0x7FFFu + ((b >> 16) & 1u)) >> 16;
}

static __device__ __forceinline__ f32x4 mfma16(uint4 a, uint4 b, f32x4 c) {
  return __builtin_amdgcn_mfma_f32_16x16x32_bf16(
      __builtin_bit_cast(s16x8, a), __builtin_bit_cast(s16x8, b), c, 0, 0, 0);
}

// scatter point indices into dense voxel LUT (codes unique per sample)
__global__ void k_scatter(const int* __restrict__ pos, int* __restrict__ lut) {
  int g = blockIdx.x * blockDim.x + threadIdx.x;
  if (g >= NROWS) return;
  int b = g / NPTS;
  int i = g - b * NPTS;
  int x = pos[3 * g], y = pos[3 * g + 1], z = pos[3 * g + 2];
  lut[(size_t)b * D3 + (x * DGRID + y) * DGRID + z] = i;
}

// count points per macro-cell (8^3 voxels)
__global__ void k_cellcount(const int* __restrict__ pos, int* __restrict__ cnt) {
  int g = blockIdx.x * blockDim.x + threadIdx.x;
  if (g >= NROWS) return;
  int b = g / NPTS;
  int cid = (b << 12) | ((pos[3 * g] >> 3) << 8) | ((pos[3 * g + 1] >> 3) << 4) |
            (pos[3 * g + 2] >> 3);
  atomicAdd(&cnt[cid], 1);
}

// exclusive prefix scan of NCELLS counters, single block
__global__ void k_scan(const int* __restrict__ cnt, int* __restrict__ cstart) {
  __shared__ int s[1024];
  int tid = threadIdx.x;
  int e[8];
  int sum = 0;
#pragma unroll
  for (int j = 0; j < 8; j++) {
    int v = cnt[tid * 8 + j];
    e[j] = sum;
    sum += v;
  }
  s[tid] = sum;
  __syncthreads();
  for (int off = 1; off < 1024; off <<= 1) {
    int t = (tid >= off) ? s[tid - off] : 0;
    __syncthreads();
    s[tid] += t;
    __syncthreads();
  }
  int base = tid ? s[tid - 1] : 0;
#pragma unroll
  for (int j = 0; j < 8; j++) cstart[tid * 8 + j] = base + e[j];
}

// scatter points into cell-sorted order; perm: sorted->orig, iperm: orig->sorted
__global__ void k_bucket(const int* __restrict__ pos, const int* __restrict__ cstart,
                         int* __restrict__ fill, int* __restrict__ perm,
                         int* __restrict__ iperm) {
  int g = blockIdx.x * blockDim.x + threadIdx.x;
  if (g >= NROWS) return;
  int b = g / NPTS;
  int cid = (b << 12) | ((pos[3 * g] >> 3) << 8) | ((pos[3 * g + 1] >> 3) << 4) |
            (pos[3 * g + 2] >> 3);
  int slot = cstart[cid] + atomicAdd(&fill[cid], 1);
  perm[slot] = g;
  iperm[g] = slot;
}

// sorted-space dense neighbor table; invalid/missing/pad -> ZROW
__global__ void k_nbr_s(const int* __restrict__ pos, const int* __restrict__ lut,
                        const int* __restrict__ perm, const int* __restrict__ iperm,
                        int* __restrict__ nbr) {
  int s = blockIdx.x * blockDim.x + threadIdx.x;
  if (s >= NPAD) return;
  if (s >= NROWS) {
#pragma unroll
    for (int t = 0; t < 27; ++t) nbr[(size_t)t * NPAD + s] = ZROW;
    return;
  }
  int g = perm[s];
  int b = g / NPTS;
  int x = pos[3 * g], y = pos[3 * g + 1], z = pos[3 * g + 2];
  const int* L = lut + (size_t)b * D3;
  const int* ip = iperm + (size_t)b * NPTS;
#pragma unroll
  for (int t = 0; t < 27; ++t) {
    int nx = x + t / 9 - 1;
    int ny = y + (t / 3) % 3 - 1;
    int nz = z + t % 3 - 1;
    int v = ZROW;
    if ((unsigned)nx < DGRID && (unsigned)ny < DGRID && (unsigned)nz < DGRID) {
      int n = L[(nx * DGRID + ny) * DGRID + nz];
      if (n >= 0) v = ip[n];
    }
    nbr[(size_t)t * NPAD + s] = v;
  }
}

// pack W into exact mfma_16x16x32_bf16 B-fragment layout:
// Wfrag[((cid*27+t)*2+s)*256 + nb*64 + lane]
__global__ void k_wpack(const float* __restrict__ Ws, uint4* __restrict__ Wfrag) {
  int e = blockIdx.x * 256 + threadIdx.x;
  if (e >= 4 * 27 * 512) return;
  int lane = e & 63, nb = (e >> 6) & 3, s = (e >> 8) & 1, tt = e >> 9;
  int kb = s * 32 + (lane >> 4) * 8;
  int cout = nb * 16 + (lane & 15);
  const float* src = Ws + (size_t)tt * 4096;
  uint32_t p[4];
#pragma unroll
  for (int j = 0; j < 4; ++j) {
    uint32_t lo = f2bf_rne(src[(kb + 2 * j) * 64 + cout]);
    uint32_t hi = f2bf_rne(src[(kb + 2 * j + 1) * 64 + cout]);
    p[j] = (hi << 16) | lo;
  }
  uint4 o;
  o.x = p[0]; o.y = p[1]; o.z = p[2]; o.w = p[3];
  Wfrag[e] = o;
}

// stage-1 BN stats over a f32 [NROWS][64] tensor (feats only; order-independent)
__global__ void k_stats1(const float* __restrict__ X, float* __restrict__ part) {
  __shared__ float s[512];
  int c = threadIdx.x & 63, q = threadIdx.x >> 6;
  float sm = 0.f, sq = 0.f;
  for (int r = blockIdx.x * 4 + q; r < NROWS; r += SBLK * 4) {
    float v = X[(size_t)r * 64 + c];
    sm += v;
    sq += v * v;
  }
  s[threadIdx.x] = sm;
  s[256 + threadIdx.x] = sq;
  __syncthreads();
  if (q == 0) {
    sm = s[c] + s[64 + c] + s[128 + c] + s[192 + c];
    sq = s[256 + c] + s[320 + c] + s[384 + c] + s[448 + c];
    part[blockIdx.x * 128 + c] = sm;
    part[blockIdx.x * 128 + 64 + c] = sq;
  }
}

// stage-2: reduce nblk partials -> affine (a, b') with bnrelu(x)=relu(x*a+b')
__global__ void k_stats2(const float* __restrict__ part, int nblk,
                         const float* __restrict__ gamma, const float* __restrict__ beta,
                         float* __restrict__ chanp, int cid) {
  __shared__ float s[512];
  int c = threadIdx.x & 63, q = threadIdx.x >> 6;
  float sm = 0.f, sq = 0.f;
  for (int rb = q; rb < nblk; rb += 4) {
    sm += part[rb * 128 + c];
    sq += part[rb * 128 + 64 + c];
  }
  s[threadIdx.x] = sm;
  s[256 + threadIdx.x] = sq;
  __syncthreads();
  if (q == 0) {
    sm = s[c] + s[64 + c] + s[128 + c] + s[192 + c];
    sq = s[256 + c] + s[320 + c] + s[384 + c] + s[448 + c];
    float mean = sm / (float)NROWS;
    float var = sq / (float)NROWS - mean * mean;
    float a = gamma[cid * 64 + c] * rsqrtf(var + EPSBN);
    chanp[cid * 128 + c] = a;
    chanp[cid * 128 + 64 + c] = beta[cid * 64 + c] - mean * a;
  }
}

// h[slot] = bnrelu(X[gperm ? gperm[slot] : slot]) as bf16; row ZROW = zeros
__global__ void k_hpass(const float* __restrict__ X, const float* __restrict__ chanp,
                        int cid, const int* __restrict__ gperm, uint4* __restrict__ h) {
  int g = blockIdx.x * blockDim.x + threadIdx.x;
  if (g >= (NROWS + 1) * 8) return;
  int row = g >> 3;
  if (row >= NROWS) {
    h[g] = (uint4){0u, 0u, 0u, 0u};
    return;
  }
  int src = gperm ? gperm[row] : row;
  int c0 = (g & 7) * 8;
  const float* cp = chanp + cid * 128;
  const float4 a0 = *(const float4*)(cp + c0);
  const float4 a1 = *(const float4*)(cp + c0 + 4);
  const float4 b0 = *(const float4*)(cp + 64 + c0);
  const float4 b1 = *(const float4*)(cp + 64 + c0 + 4);
  const float* Xr = X + (size_t)src * 64 + c0;
  const float4 x0 = *(const float4*)Xr;
  const float4 x1 = *(const float4*)(Xr + 4);
  float v0 = fmaxf(fmaf(x0.x, a0.x, b0.x), 0.f);
  float v1 = fmaxf(fmaf(x0.y, a0.y, b0.y), 0.f);
  float v2 = fmaxf(fmaf(x0.z, a0.z, b0.z), 0.f);
  float v3 = fmaxf(fmaf(x0.w, a0.w, b0.w), 0.f);
  float v4 = fmaxf(fmaf(x1.x, a1.x, b1.x), 0.f);
  float v5 = fmaxf(fmaf(x1.y, a1.y, b1.y), 0.f);
  float v6 = fmaxf(fmaf(x1.z, a1.z, b1.z), 0.f);
  float v7 = fmaxf(fmaf(x1.w, a1.w, b1.w), 0.f);
  uint4 o;
  o.x = (f2bf_rne(v1) << 16) | f2bf_rne(v0);
  o.y = (f2bf_rne(v3) << 16) | f2bf_rne(v2);
  o.z = (f2bf_rne(v5) << 16) | f2bf_rne(v4);
  o.w = (f2bf_rne(v7) << 16) | f2bf_rne(v6);
  h[g] = o;
}

// One pipeline phase (tap T), period-3 buffer rotation.
// Issue order (FIFO-safe): W(T+1) first, then ni(T+4), then A(T+2) (addresses
// from NIU = ni(T+2), loaded 2 phases ago). MFMA(T) waits on WU (1 phase old)
// and AU (2 phases old); younger prefetches stay in flight.
#define PH(T, WU, WL, AU, AL, NIU, NIL)                                     \
  {                                                                         \
    int tw = (T) + 1 <= 26 ? (T) + 1 : 26;                                  \
    const uint4* Wt = Wf + (size_t)tw * 512 + lane;                         \
    _Pragma("unroll") for (int i = 0; i < 8; i++) WL[i] = Wt[i * 64];       \
    int tn = (T) + 4 <= 26 ? (T) + 4 : 26;                                  \
    _Pragma("unroll") for (int rt = 0; rt < 2; rt++)                        \
        NIL[rt] = nbp[(size_t)tn * NPAD + rt * 16];                         \
    {                                                                       \
      const uint4* hp0 = h + (size_t)NIU[0] * 8 + lkg;                      \
      const uint4* hp1 = h + (size_t)NIU[1] * 8 + lkg;                      \
      AL[0][0] = hp0[0]; AL[0][1] = hp0[4];                                 \
      AL[1][0] = hp1[0]; AL[1][1] = hp1[4];                                 \
    }                                                                       \
    _Pragma("unroll") for (int s = 0; s < 2; s++)                           \
      _Pragma("unroll") for (int rt = 0; rt < 2; rt++)                      \
        _Pragma("unroll") for (int nb = 0; nb < 4; nb++)                    \
          acc[rt][nb] = mfma16(AU[rt][s], WU[s * 4 + nb], acc[rt][nb]);     \
  }

// MFMA conv in sorted space: wave = 32 rows x 64 cout; dense 27 taps;
// branchless zero-row gathers (L1-local thanks to spatial sort);
// W depth-1 / A depth-2 / ni depth-2 register pipeline, period-3 rotation.
__global__ __launch_bounds__(256, 2) void k_conv(
    const uint4* __restrict__ h, const uint4* __restrict__ Wf,
    const int* __restrict__ nbr, const float* __restrict__ res,
    const int* __restrict__ rperm, float* __restrict__ out,
    const int* __restrict__ wperm, float* __restrict__ part, int do_stats) {
  __shared__ float xp[4][16 * 68];
  __shared__ float sred[2][4][4][16];
  int tid = threadIdx.x, wv = tid >> 6, lane = tid & 63;
  int tbase = (blockIdx.x * 4 + wv) * 32;
  int lrow = lane & 15, lkg = lane >> 4;

  f32x4 acc[2][4];
#pragma unroll
  for (int i = 0; i < 2; i++)
#pragma unroll
    for (int j = 0; j < 4; j++) acc[i][j] = (f32x4){0.f, 0.f, 0.f, 0.f};

  const int* nbp = nbr + tbase + lrow;
  int niA[2], niB[2], niC[2];
  uint4 wA[8], wB[8], wC[8];
  uint4 aA[2][2], aB[2][2], aC[2][2];

  // prologue: W(0)->wA; ni(0),ni(1) temps; ni(2)->niA; ni(3)->niB; A(0)->aA; A(1)->aB
  int p0[2], p1[2];
#pragma unroll
  for (int i = 0; i < 8; i++) wA[i] = Wf[i * 64 + lane];
#pragma unroll
  for (int rt = 0; rt < 2; rt++) p0[rt] = nbp[rt * 16];
#pragma unroll
  for (int rt = 0; rt < 2; rt++) p1[rt] = nbp[(size_t)NPAD + rt * 16];
#pragma unroll
  for (int rt = 0; rt < 2; rt++) niA[rt] = nbp[(size_t)2 * NPAD + rt * 16];
#pragma unroll
  for (int rt = 0; rt < 2; rt++) niB[rt] = nbp[(size_t)3 * NPAD + rt * 16];
  {
    const uint4* hp0 = h + (size_t)p0[0] * 8 + lkg;
    const uint4* hp1 = h + (size_t)p0[1] * 8 + lkg;
    aA[0][0] = hp0[0]; aA[0][1] = hp0[4];
    aA[1][0] = hp1[0]; aA[1][1] = hp1[4];
  }
  {
    const uint4* hp0 = h + (size_t)p1[0] * 8 + lkg;
    const uint4* hp1 = h + (size_t)p1[1] * 8 + lkg;
    aB[0][0] = hp0[0]; aB[0][1] = hp0[4];
    aB[1][0] = hp1[0]; aB[1][1] = hp1[4];
  }

  for (int t = 0; t < 27; t += 3) {
    PH(t, wA, wB, aA, aC, niA, niC)
    PH(t + 1, wB, wC, aB, aA, niB, niA)
    PH(t + 2, wC, wA, aC, aB, niC, niB)
  }

  // ---- epilogue: per-rt LDS transpose -> coalesced res/out, fused stats
  float smc[16], sqc[16];
#pragma unroll
  for (int j = 0; j < 16; j++) smc[j] = sqc[j] = 0.f;
  float* slab = xp[wv];
#pragma unroll 1
  for (int rt = 0; rt < 2; rt++) {
#pragma unroll
    for (int nb = 0; nb < 4; nb++)
#pragma unroll
      for (int r = 0; r < 4; r++)
        slab[(lkg * 4 + r) * 68 + nb * 16 + lrow] = acc[rt][nb][r];
    __syncthreads();
    int gr = tbase + rt * 16 + lrow;
    if (gr < NROWS) {
      int rowr = rperm ? rperm[gr] : gr;
      int roww = wperm ? wperm[gr] : gr;
#pragma unroll
      for (int j = 0; j < 4; j++) {
        float4 vv = *(float4*)&slab[lrow * 68 + lkg * 16 + j * 4];
        size_t cofs = (size_t)(lkg * 16 + j * 4);
        if (res) {
          float4 rr = *(const float4*)(res + (size_t)rowr * 64 + cofs);
          vv.x += rr.x; vv.y += rr.y; vv.z += rr.z; vv.w += rr.w;
        }
        *(float4*)(out + (size_t)roww * 64 + cofs) = vv;
        smc[j * 4 + 0] += vv.x; sqc[j * 4 + 0] += vv.x * vv.x;
        smc[j * 4 + 1] += vv.y; sqc[j * 4 + 1] += vv.y * vv.y;
        smc[j * 4 + 2] += vv.z; sqc[j * 4 + 2] += vv.z * vv.z;
        smc[j * 4 + 3] += vv.w; sqc[j * 4 + 3] += vv.w * vv.w;
      }
    }
    __syncthreads();
  }
  if (do_stats) {
#pragma unroll
    for (int j = 0; j < 16; j++) {
      smc[j] += __shfl_xor(smc[j], 1); sqc[j] += __shfl_xor(sqc[j], 1);
      smc[j] += __shfl_xor(smc[j], 2); sqc[j] += __shfl_xor(sqc[j], 2);
      smc[j] += __shfl_xor(smc[j], 4); sqc[j] += __shfl_xor(sqc[j], 4);
      smc[j] += __shfl_xor(smc[j], 8); sqc[j] += __shfl_xor(sqc[j], 8);
    }
    if (lrow == 0) {
#pragma unroll
      for (int j = 0; j < 16; j++) {
        sred[0][wv][lkg][j] = smc[j];
        sred[1][wv][lkg][j] = sqc[j];
      }
    }
    __syncthreads();
    if (tid < 64) {
      float s0 = 0.f, s1 = 0.f;
      int q = tid >> 4, c = tid & 15;
#pragma unroll
      for (int w = 0; w < 4; w++) {
        s0 += sred[0][w][q][c];
        s1 += sred[1][w][q][c];
      }
      part[blockIdx.x * 128 + tid] = s0;
      part[blockIdx.x * 128 + 64 + tid] = s1;
    }
  }
}

extern "C" void kernel_launch(void* const* d_in, const int* in_sizes, int n_in,
                              void* d_out, int out_size, void* d_ws, size_t ws_size,
                              hipStream_t stream) {
  const float* feats = (const float*)d_in[0];
  const float* Ws = (const float*)d_in[1];
  const float* gammas = (const float*)d_in[2];
  const float* betas = (const float*)d_in[3];
  const int* pos = (const int*)d_in[4];
  float* out = (float*)d_out;

  char* w = (char*)d_ws;
  auto alloc = [&](size_t b) {
    char* p = w;
    w += (b + 255) & ~(size_t)255;
    return p;
  };
  int* nbr = (int*)alloc((size_t)27 * NPAD * 4);           // 32.4 MB
  uint4* Wfrag = (uint4*)alloc((size_t)4 * 27 * 512 * 16); // 0.9 MB
  float* part = (float*)alloc((size_t)NCBLK * 128 * 4);    // 1.2 MB
  float* chanp = (float*)alloc((size_t)4 * 128 * 4);       // 2 KB
  int* perm = (int*)alloc((size_t)NPAD * 4);               // 1.2 MB
  int* iperm = (int*)alloc((size_t)NROWS * 4);             // 1.2 MB
  int* ccnt = (int*)alloc((size_t)NCELLS * 4);             // 32 KB
  int* cfill = (int*)alloc((size_t)NCELLS * 4);            // 32 KB
  int* cstart = (int*)alloc((size_t)NCELLS * 4);           // 32 KB
  uint4* h = (uint4*)alloc((size_t)NPAD * 128);            // 38.4 MB
  float* xbuf = (float*)alloc((size_t)NROWS * 64 * 4);     // 76.8 MB
  char* reg0 = alloc((size_t)NROWS * 64 * 4);              // 76.8 MB
  float* cbuf = (float*)reg0;
  int* lut = (int*)reg0;  // lut (16.8 MB) dead before cbuf first written

  hipMemsetAsync(lut, 0xFF, (size_t)NBATCH * D3 * 4, stream);
  hipMemsetAsync(ccnt, 0, (size_t)NCELLS * 8, stream);  // ccnt + cfill (adjacent)
  int gpts = (NROWS + 255) / 256;
  k_scatter<<<gpts, 256, 0, stream>>>(pos, lut);
  k_cellcount<<<gpts, 256, 0, stream>>>(pos, ccnt);
  k_scan<<<1, 1024, 0, stream>>>(ccnt, cstart);
  k_bucket<<<gpts, 256, 0, stream>>>(pos, cstart, cfill, perm, iperm);
  k_nbr_s<<<NPAD / 256, 256, 0, stream>>>(pos, lut, perm, iperm, nbr);
  k_wpack<<<216, 256, 0, stream>>>(Ws, Wfrag);

  k_stats1<<<SBLK, 256, 0, stream>>>(feats, part);
  k_stats2<<<1, 256, 0, stream>>>(part, SBLK, gammas, betas, chanp, 0);
  k_hpass<<<9376, 256, 0, stream>>>(feats, chanp, 0, perm, h);
  k_conv<<<NCBLK, 256, 0, stream>>>(h, Wfrag + 0 * 27 * 512, nbr, nullptr, nullptr,
                                    cbuf, nullptr, part, 1);

  k_stats2<<<1, 256, 0, stream>>>(part, NCBLK, gammas, betas, chanp, 1);
  k_hpass<<<9376, 256, 0, stream>>>(cbuf, chanp, 1, nullptr, h);
  k_conv<<<NCBLK, 256, 0, stream>>>(h, Wfrag + 1 * 27 * 512, nbr, feats, perm,
                                    xbuf, nullptr, part, 1);

  k_stats2<<<1, 256, 0, stream>>>(part, NCBLK, gammas, betas, chanp, 2);
  k_hpass<<<9376, 256, 0, stream>>>(xbuf, chanp, 2, nullptr, h);
  k_conv<<<NCBLK, 256, 0, stream>>>(h, Wfrag + 2 * 27 * 512, nbr, nullptr, nullptr,
                                    cbuf, nullptr, part, 1);

  k_stats2<<<1, 256, 0, stream>>>(part, NCBLK, gammas, betas, chanp, 3);
  k_hpass<<<9376, 256, 0, stream>>>(cbuf, chanp, 3, nullptr, h);
  k_conv<<<NCBLK, 256, 0, stream>>>(h, Wfrag + 3 * 27 * 512, nbr, xbuf, nullptr,
                                    out, perm, part, 0);
}